// Round 4
// baseline (283.498 us; speedup 1.0000x reference)
//
#include <hip/hip_runtime.h>
#include <stdint.h>
#include <math.h>

// ---------------------------------------------------------------------------
// HardNegativeMiner round 15b: wave-private staging, ZERO barriers.
// (Resubmit of r15 — container failed twice before running the kernel;
// audit found no fault/hang path: all offsets bounded, no spin loops, no
// cross-wave coupling, WAR closed by lgkmcnt(0) before DMA issue.)
// Invariant found r12-r14: VALUBusy*dur ~= 140-143 us in all schedules ->
// that's the irreducible threefry/gumbel VALU work; everything above it is
// stall. r12's 56 us of stall = 16 barrier drains/block + epilogue tail +
// 6.5-round dispatch raggedness. r14 lesson: this kernel is structurally
// 4-waves/SIMD (live ~124 regs); forcing 5 spills (WRITE 46 MB).
// This round: 64-thread blocks; each wave owns a private 32x64 tile and
// 12 KB LDS (A 32 rows + B 64 rows, hi/lo, K-chunks of 32). No cross-wave
// sharing -> no __syncthreads at all. Per chunk: vmcnt(0) (own DMAs, issued
// ~800 cyc earlier -> free) -> ds_read frags -> 4 gumbels (pad read latency)
// -> lgkmcnt(0) fence (closes the same-buffer WAR hazard: DMA return-write
// cannot precede its issue) -> issue next chunk's 12 DMAs -> 24 MFMAs.
// 13 blocks/CU (LDS-bound) = 3.25 indep waves/SIMD; grid 26624 = exactly
// 8 rounds -> no tail. 2x L2 traffic (~14 TB/s agg, ceiling 34.5) is the
// price; HBM unchanged (L3-served).
// GEMM/gumbel/epilogue arithmetic bit-identical to r12.
// PRNG chain (partitionable threefry) verified bit-exact in rounds 1-14.
// ---------------------------------------------------------------------------
#define BN 16384   // batch
#define DK 256     // dim
#define NH 3276    // int(16384*0.2)
#define NJT 104    // j-tiles of 32 (104*32 = 3328 >= NH)
#define NCT 256    // c-tiles of 64
#define NTILE (NJT * NCT)   // 26624 = 8 * 3328 = 8 rounds at 13 blocks/CU

typedef __attribute__((ext_vector_type(8))) short short8;
typedef __attribute__((ext_vector_type(4))) short short4v;
typedef __attribute__((ext_vector_type(4))) float f32x4;

__host__ __device__ __forceinline__ void tf2x32(uint32_t k0, uint32_t k1,
                                                uint32_t c0, uint32_t c1,
                                                uint32_t& o0, uint32_t& o1) {
  uint32_t ks2 = 0x1BD11BDAu ^ k0 ^ k1;
  uint32_t x0 = c0 + k0, x1 = c1 + k1;
#define RR(d) { x0 += x1; x1 = __builtin_rotateleft32(x1, d); x1 ^= x0; }
  RR(13) RR(15) RR(26) RR(6)   x0 += k1;  x1 += ks2 + 1u;
  RR(17) RR(29) RR(16) RR(24)  x0 += ks2; x1 += k0  + 2u;
  RR(13) RR(15) RR(26) RR(6)   x0 += k0;  x1 += k1  + 3u;
  RR(17) RR(29) RR(16) RR(24)  x0 += k1;  x1 += ks2 + 4u;
  RR(13) RR(15) RR(26) RR(6)   x0 += ks2; x1 += k0  + 5u;
#undef RR
  o0 = x0; o1 = x1;
}

__device__ __forceinline__ uint32_t rand32_at(uint32_t k0, uint32_t k1, uint32_t p) {
  uint32_t x0, x1; tf2x32(k0, k1, 0u, p, x0, x1);
  return x0 ^ x1;
}

__device__ __forceinline__ float unif01_from_bits(uint32_t bits) {
  return __uint_as_float((bits >> 9) | 0x3f800000u) - 1.0f;
}

// gumbel at flat counter p: -log(-log(max(u, tiny))), fast v_log_f32 path
__device__ __forceinline__ float gumbel_at(uint32_t k0, uint32_t k1, uint32_t p) {
  uint32_t bits = rand32_at(k0, k1, p);
  float f = unif01_from_bits(bits);
  float u = fmaxf(f, 1.17549435e-38f);             // minval = finfo(f32).tiny
  float t = __log2f(u) * (-0.69314718055994531f);  // -ln(u) > 0
  return __log2f(t) * (-0.69314718055994531f);     // -ln(t)
}

// monotonic float->u32; pack (value, ~col): max => larger val, tie => smaller col
__device__ __forceinline__ unsigned long long packvc(float v, uint32_t c) {
  uint32_t u = __float_as_uint(v);
  u ^= ((int32_t)u < 0) ? 0xFFFFFFFFu : 0x80000000u;
  return ((unsigned long long)u << 32) | (unsigned long long)(~c);
}

// 16-byte global -> LDS async DMA. LDS dest is wave-uniform base + lane*16.
__device__ __forceinline__ void glds16(const unsigned short* g, short* l) {
  __builtin_amdgcn_global_load_lds(
      (const __attribute__((address_space(1))) void*)g,
      (__attribute__((address_space(3))) void*)l, 16, 0, 0);
}

// ---------------------------------------------------------------------------
// Fused: row inv-norm + split-bf16 copy of z*inv (GEMM acc == sim directly)
// + src_idx/best setup.
__global__ __launch_bounds__(256) void k_prep(const float* __restrict__ z,
                                              unsigned short* __restrict__ zh,
                                              unsigned short* __restrict__ zl,
                                              int* __restrict__ src_idx,
                                              unsigned long long* __restrict__ best,
                                              uint32_t k20, uint32_t k21) {
  int b = blockIdx.x, t = threadIdx.x;
  if (b < BN / 4) {
    int row = b * 4 + (t >> 6), lane = t & 63;
    float4 v = *(const float4*)&z[row * DK + lane * 4];
    float ss = v.x * v.x + v.y * v.y + v.z * v.z + v.w * v.w;
#pragma unroll
    for (int off = 32; off; off >>= 1) ss += __shfl_xor(ss, off, 64);
    float inv = 1.0f / fmaxf(sqrtf(ss), 1e-12f);
    float f[4] = {v.x * inv, v.y * inv, v.z * inv, v.w * inv};
    short4v h, l;
#pragma unroll
    for (int i = 0; i < 4; ++i) {
      uint32_t u = __float_as_uint(f[i]);
      h[i] = (short)(u >> 16);
      float r = f[i] - __uint_as_float(u & 0xFFFF0000u);
      l[i] = (short)(__float_as_uint(r) >> 16);
    }
    *(short4v*)&zh[row * DK + lane * 4] = h;
    *(short4v*)&zl[row * DK + lane * 4] = l;
  } else {
    int i = (b - BN / 4) * 256 + t;
    if (i < NH) {
      uint32_t bits = rand32_at(k20, k21, (uint32_t)i);
      src_idx[i] = (int)(bits & (uint32_t)(BN - 1));  // randint span 2^14
      best[i] = 0ull;                                 // identity for packvc keys
    }
  }
}

// ---------------------------------------------------------------------------
// One wave per block; private 32x64 tile; K=256 in 8 chunks of 32.
// LDS rows of 32 shorts; 16B unit u stored at u ^ ((row>>1)&3); DMA source
// addresses carry the inverse swizzle (identical scheme to r12, 0 conflicts).
__global__ __launch_bounds__(64, 3) void k_main(const unsigned short* __restrict__ zh,
                                                const unsigned short* __restrict__ zl,
                                                const int* __restrict__ src_idx,
                                                unsigned long long* __restrict__ best,
                                                uint32_t kt0, uint32_t kt1) {
  __shared__ __align__(16) short As_hi[32 * 32];    // 2 KB
  __shared__ __align__(16) short As_lo[32 * 32];    // 2 KB
  __shared__ __align__(16) short Bs_hi[64 * 32];    // 4 KB
  __shared__ __align__(16) short Bs_lo[64 * 32];    // 4 KB

  // XCD-aware swizzle: XCD x owns c-tiles [32x, 32x+32) -> 2 MB B-set per L2
  const int flat = blockIdx.x;                 // 26624 = 8 * (32 * 104)
  const int xcd = flat & 7, slot = flat >> 3;  // slot in [0, 3328)
  const int c_base = (xcd * 32 + (slot & 31)) * 64;
  const int j_base = (slot >> 5) * 32;

  const int lane = threadIdx.x & 63;

  // staging: rows r0, r0+16 (A) and 16s+r0 (B); unit swizzle is row-periodic-8
  // so (row>>1)&3 == (r0>>1)&3 for all strips -> single u per lane.
  const int r0 = lane >> 2;
  const int u = (lane & 3) ^ ((r0 >> 1) & 3);
  const uint32_t offA0 = (uint32_t)(src_idx[min(j_base + r0,      NH - 1)] * DK + u * 8);
  const uint32_t offA1 = (uint32_t)(src_idx[min(j_base + 16 + r0, NH - 1)] * DK + u * 8);
  const uint32_t offB0 = (uint32_t)((c_base +  0 + r0) * DK + u * 8);
  const uint32_t offB1 = (uint32_t)((c_base + 16 + r0) * DK + u * 8);
  const uint32_t offB2 = (uint32_t)((c_base + 32 + r0) * DK + u * 8);
  const uint32_t offB3 = (uint32_t)((c_base + 48 + r0) * DK + u * 8);

  // fragment roles
  const int cl = lane & 15, q = lane >> 4;
  int foffA[2], foffB[4];
#pragma unroll
  for (int i = 0; i < 2; ++i) {
    int r = cl + i * 16;
    foffA[i] = r * 32 + (q ^ ((r >> 1) & 3)) * 8;
  }
#pragma unroll
  for (int i = 0; i < 4; ++i) {
    int r = cl + i * 16;
    foffB[i] = r * 32 + (q ^ ((r >> 1) & 3)) * 8;
  }

  // epilogue coordinates (also used for in-loop gumbel counters)
  const int q4 = q * 4;
  const int roff = j_base;
  const uint32_t ccl = (uint32_t)(c_base + cl);

  f32x4 acc[2][4];
#pragma unroll
  for (int mt = 0; mt < 2; ++mt)
#pragma unroll
    for (int nt = 0; nt < 4; ++nt) acc[mt][nt] = (f32x4){0.f, 0.f, 0.f, 0.f};

  float gum[32];   // gum[((mt*4+r)*4)+nt], filled 4 per K-chunk

  auto stage = [&](int ko) {   // ko in shorts; folds to 13-bit imm offsets
    glds16(zh + offA0 + ko, As_hi);
    glds16(zh + offA1 + ko, As_hi + 512);
    glds16(zl + offA0 + ko, As_lo);
    glds16(zl + offA1 + ko, As_lo + 512);
    glds16(zh + offB0 + ko, Bs_hi);
    glds16(zh + offB1 + ko, Bs_hi + 512);
    glds16(zh + offB2 + ko, Bs_hi + 1024);
    glds16(zh + offB3 + ko, Bs_hi + 1536);
    glds16(zl + offB0 + ko, Bs_lo);
    glds16(zl + offB1 + ko, Bs_lo + 512);
    glds16(zl + offB2 + ko, Bs_lo + 1024);
    glds16(zl + offB3 + ko, Bs_lo + 1536);
  };

  // prologue: DMA chunk 0
  stage(0);

#pragma unroll
  for (int kc = 0; kc < 8; ++kc) {
    // own DMAs were issued a full compute phase ago -> ~zero exposed wait
    __builtin_amdgcn_sched_barrier(0);
    asm volatile("s_waitcnt vmcnt(0)" ::: "memory");
    __builtin_amdgcn_sched_barrier(0);

    short8 ah[2], al[2], bh[4], bl[4];
#pragma unroll
    for (int nt = 0; nt < 4; ++nt) {
      bh[nt] = *(const short8*)&Bs_hi[foffB[nt]];
      bl[nt] = *(const short8*)&Bs_lo[foffB[nt]];
    }
#pragma unroll
    for (int mt = 0; mt < 2; ++mt) {
      ah[mt] = *(const short8*)&As_hi[foffA[mt]];
      al[mt] = *(const short8*)&As_lo[foffA[mt]];
    }

    // ---- gumbels pad the ds_read latency: pure-VALU, no LDS access ----
#pragma unroll
    for (int i = 0; i < 4; ++i) {
      const int idx = kc * 4 + i;
      const int mt = idx >> 4, r = (idx >> 2) & 3, nt = idx & 3;
      int gj = roff + mt * 16 + q4 + r;
      uint32_t p = (uint32_t)gj * (uint32_t)BN + ccl + (uint32_t)(nt * 16);
      float gv = gumbel_at(kt0, kt1, p);
      asm volatile("" : "+v"(gv));
      gum[idx] = gv;
    }

    // frag reads are complete past this fence -> safe to overwrite LDS.
    // (DMA return-write cannot precede DMA issue, which is below the fence.)
    __builtin_amdgcn_sched_barrier(0);
    asm volatile("s_waitcnt lgkmcnt(0)" ::: "memory");
    __builtin_amdgcn_sched_barrier(0);

    if (kc < 7) stage((kc + 1) * 32);   // lands during MFMAs + next gumbels

#pragma unroll
    for (int mt = 0; mt < 2; ++mt)
#pragma unroll
      for (int nt = 0; nt < 4; ++nt) {
        acc[mt][nt] = __builtin_amdgcn_mfma_f32_16x16x32_bf16(ah[mt], bh[nt], acc[mt][nt], 0, 0, 0);
        acc[mt][nt] = __builtin_amdgcn_mfma_f32_16x16x32_bf16(ah[mt], bl[nt], acc[mt][nt], 0, 0, 0);
        acc[mt][nt] = __builtin_amdgcn_mfma_f32_16x16x32_bf16(al[mt], bh[nt], acc[mt][nt], 0, 0, 0);
      }
  }

  // ---- lean epilogue: tot = fmaf(sim,10,gum); argmax over wave's 64 cols ----
#pragma unroll
  for (int mt = 0; mt < 2; ++mt)
#pragma unroll
    for (int r = 0; r < 4; ++r) {
      int gj = roff + mt * 16 + q4 + r;
      int s = src_idx[min(gj, NH - 1)];
      float bv = -INFINITY; uint32_t bc = 0;
#pragma unroll
      for (int nt = 0; nt < 4; ++nt) {
        uint32_t c = ccl + (uint32_t)(nt * 16);
        float tot = fmaf(acc[mt][nt][r], 10.0f, gum[((mt * 4 + r) * 4) + nt]);
        tot = ((int)c == s) ? -INFINITY : tot;         // diagonal mask
        if (tot > bv) { bv = tot; bc = c; }
      }
      unsigned long long key = packvc(bv, bc);
#pragma unroll
      for (int off = 1; off <= 8; off <<= 1) {        // reduce over 16 cl lanes
        unsigned long long o = __shfl_xor(key, off, 64);
        if (o > key) key = o;
      }
      if (cl == 0 && gj < NH) atomicMax(&best[gj], key);
    }
}

__global__ __launch_bounds__(64) void k_out(const float* __restrict__ z,
                                            const int* __restrict__ src_idx,
                                            const unsigned long long* __restrict__ best,
                                            float* __restrict__ out,
                                            uint32_t ka0, uint32_t ka1) {
  int j = blockIdx.x;
  int lane = threadIdx.x;
  int s = src_idx[j];
  int tgt = (int)(~((uint32_t)(best[j] & 0xFFFFFFFFull)));
  uint32_t bits = rand32_at(ka0, ka1, (uint32_t)j);
  float alpha = unif01_from_bits(bits) * 0.5f;   // uniform * MIX_ALPHA
  float om = 1.0f - alpha;
  float4 a = *(const float4*)&z[s * DK + lane * 4];
  float4 b = *(const float4*)&z[tgt * DK + lane * 4];
  float4 o;
  o.x = alpha * a.x + om * b.x;
  o.y = alpha * a.y + om * b.y;
  o.z = alpha * a.z + om * b.z;
  o.w = alpha * a.w + om * b.w;
  *(float4*)&out[j * DK + lane * 4] = o;
}

// ---------------------------------------------------------------------------
extern "C" void kernel_launch(void* const* d_in, const int* in_sizes, int n_in,
                              void* d_out, int out_size, void* d_ws, size_t ws_size,
                              hipStream_t stream) {
  const float* z = (const float*)d_in[0];
  float* out = (float*)d_out;
  char* ws = (char*)d_ws;
  // ws layout (~16.8 MB):
  int*                src_idx = (int*)(ws);                        // 16 KB
  unsigned long long* best    = (unsigned long long*)(ws + 16384); // 32 KB
  unsigned short*     zh      = (unsigned short*)(ws + 65536);     // 8.39 MB
  unsigned short*     zl      = (unsigned short*)(ws + 65536 + 8388608);

  // host-side threefry key derivation (partitionable scheme, verified round 1)
  uint32_t r0 = 0u, r1 = 42u;
  uint32_t ks0, ks1, kt0, kt1, ka0, ka1, k20, k21;
  tf2x32(r0, r1, 0u, 0u, ks0, ks1);   // k_src   = split(root,3)[0]
  tf2x32(r0, r1, 0u, 1u, kt0, kt1);   // k_tgt   = split(root,3)[1]
  tf2x32(r0, r1, 0u, 2u, ka0, ka1);   // k_alpha = split(root,3)[2]
  tf2x32(ks0, ks1, 0u, 1u, k20, k21); // split(k_src,2)[1] (randint lower bits)

  k_prep<<<dim3(BN / 4 + (NH + 255) / 256), dim3(256), 0, stream>>>(
      z, zh, zl, src_idx, best, k20, k21);
  k_main<<<dim3(NTILE), dim3(64), 0, stream>>>(zh, zl, src_idx, best, kt0, kt1);
  k_out <<<dim3(NH), dim3(64), 0, stream>>>(z, src_idx, best, out, ka0, ka1);
}

// Round 5
// 254.209 us; speedup vs baseline: 1.1152x; 1.1152x over previous
//
#include <hip/hip_runtime.h>
#include <stdint.h>
#include <math.h>

// ---------------------------------------------------------------------------
// HardNegativeMiner round 16: r12 (199 us, best of 4 structural variants)
// with two scheduling-only edits:
//  (1) per-chunk gumbels split 2+2: chains 0-1 moved between the frag
//      ds_reads and barrier2 (their VALU work covers the LDS read latency
//      that barrier2's lgkmcnt(0) drain previously exposed); chains 2-3
//      stay after the DMA issue, interleaved with the MFMAs (cover DMA
//      latency into next barrier1).
//  (2) one asm-volatile pin per PAIR (was per gumbel): volatile asm is a
//      scheduler wall; merging pins lets the two independent threefry
//      chains interleave (fills int-ALU dep-chain bubbles) while still
//      pinning them in-loop.
// Evidence base: r12-r15 all have VALUBusy*dur ~= 143-149 us (schedule-
// invariant busy floor); r12's 56 us idle = exposed ds_read latency at
// barrier2 + pin-serialized chains + barrier skew. r13 (no LDS) = 349,
// r14 ((256,5) epilogue gumbels) = 226 + spill, r15 (wave-private, 12->16KB
// LDS granularity rounding -> 10 waves/CU) = 239. Structure locked to r12.
// PRNG chain (partitionable threefry) verified bit-exact in rounds 1-15.
// ---------------------------------------------------------------------------
#define BN 16384   // batch
#define DK 256     // dim
#define NH 3276    // int(16384*0.2)
#define NJB 52     // j-strips of 64 (52*64 = 3328 >= NH)
#define NCB 128    // c-blocks of 128
#define NTILE (NJB * NCB)   // 6656 = 8 * 832

typedef __attribute__((ext_vector_type(8))) short short8;
typedef __attribute__((ext_vector_type(4))) short short4v;
typedef __attribute__((ext_vector_type(4))) float f32x4;

__host__ __device__ __forceinline__ void tf2x32(uint32_t k0, uint32_t k1,
                                                uint32_t c0, uint32_t c1,
                                                uint32_t& o0, uint32_t& o1) {
  uint32_t ks2 = 0x1BD11BDAu ^ k0 ^ k1;
  uint32_t x0 = c0 + k0, x1 = c1 + k1;
#define RR(d) { x0 += x1; x1 = __builtin_rotateleft32(x1, d); x1 ^= x0; }
  RR(13) RR(15) RR(26) RR(6)   x0 += k1;  x1 += ks2 + 1u;
  RR(17) RR(29) RR(16) RR(24)  x0 += ks2; x1 += k0  + 2u;
  RR(13) RR(15) RR(26) RR(6)   x0 += k0;  x1 += k1  + 3u;
  RR(17) RR(29) RR(16) RR(24)  x0 += k1;  x1 += ks2 + 4u;
  RR(13) RR(15) RR(26) RR(6)   x0 += ks2; x1 += k0  + 5u;
#undef RR
  o0 = x0; o1 = x1;
}

__device__ __forceinline__ uint32_t rand32_at(uint32_t k0, uint32_t k1, uint32_t p) {
  uint32_t x0, x1; tf2x32(k0, k1, 0u, p, x0, x1);
  return x0 ^ x1;
}

__device__ __forceinline__ float unif01_from_bits(uint32_t bits) {
  return __uint_as_float((bits >> 9) | 0x3f800000u) - 1.0f;
}

// gumbel at flat counter p: -log(-log(max(u, tiny))), fast v_log_f32 path
__device__ __forceinline__ float gumbel_at(uint32_t k0, uint32_t k1, uint32_t p) {
  uint32_t bits = rand32_at(k0, k1, p);
  float f = unif01_from_bits(bits);
  float u = fmaxf(f, 1.17549435e-38f);             // minval = finfo(f32).tiny
  float t = __log2f(u) * (-0.69314718055994531f);  // -ln(u) > 0
  return __log2f(t) * (-0.69314718055994531f);     // -ln(t)
}

// monotonic float->u32; pack (value, ~col): max => larger val, tie => smaller col
__device__ __forceinline__ unsigned long long packvc(float v, uint32_t c) {
  uint32_t u = __float_as_uint(v);
  u ^= ((int32_t)u < 0) ? 0xFFFFFFFFu : 0x80000000u;
  return ((unsigned long long)u << 32) | (unsigned long long)(~c);
}

// 16-byte global -> LDS async DMA. LDS dest is wave-uniform base + lane*16.
__device__ __forceinline__ void glds16(const unsigned short* g, short* l) {
  __builtin_amdgcn_global_load_lds(
      (const __attribute__((address_space(1))) void*)g,
      (__attribute__((address_space(3))) void*)l, 16, 0, 0);
}

// ---------------------------------------------------------------------------
// Fused: row inv-norm + split-bf16 copy of z*inv (GEMM acc == sim directly)
// + src_idx/best setup.
__global__ __launch_bounds__(256) void k_prep(const float* __restrict__ z,
                                              unsigned short* __restrict__ zh,
                                              unsigned short* __restrict__ zl,
                                              int* __restrict__ src_idx,
                                              unsigned long long* __restrict__ best,
                                              uint32_t k20, uint32_t k21) {
  int b = blockIdx.x, t = threadIdx.x;
  if (b < BN / 4) {
    int row = b * 4 + (t >> 6), lane = t & 63;
    float4 v = *(const float4*)&z[row * DK + lane * 4];
    float ss = v.x * v.x + v.y * v.y + v.z * v.z + v.w * v.w;
#pragma unroll
    for (int off = 32; off; off >>= 1) ss += __shfl_xor(ss, off, 64);
    float inv = 1.0f / fmaxf(sqrtf(ss), 1e-12f);
    float f[4] = {v.x * inv, v.y * inv, v.z * inv, v.w * inv};
    short4v h, l;
#pragma unroll
    for (int i = 0; i < 4; ++i) {
      uint32_t u = __float_as_uint(f[i]);
      h[i] = (short)(u >> 16);
      float r = f[i] - __uint_as_float(u & 0xFFFF0000u);
      l[i] = (short)(__float_as_uint(r) >> 16);
    }
    *(short4v*)&zh[row * DK + lane * 4] = h;
    *(short4v*)&zl[row * DK + lane * 4] = l;
  } else {
    int i = (b - BN / 4) * 256 + t;
    if (i < NH) {
      uint32_t bits = rand32_at(k20, k21, (uint32_t)i);
      src_idx[i] = (int)(bits & (uint32_t)(BN - 1));  // randint span 2^14
      best[i] = 0ull;                                 // identity for packvc keys
    }
  }
}

// ---------------------------------------------------------------------------
// 64x128 tile, 4 waves of 32x64. K=256 in 8 chunks of 32, split-barrier
// pipelined: barrier1 (DMA landed) -> ds_read frags -> gumbels 0,1 (cover
// read latency) -> barrier2 (LDS free; lgkm drain now costless) -> issue
// next chunk's DMA -> MFMA + gumbels 2,3 (cover DMA latency).
// LDS rows of 32 shorts; 16B unit u stored at u ^ ((row>>1)&3); DMA source
// addresses carry the inverse swizzle.
__global__ __launch_bounds__(256, 4) void k_main(const unsigned short* __restrict__ zh,
                                                 const unsigned short* __restrict__ zl,
                                                 const int* __restrict__ src_idx,
                                                 unsigned long long* __restrict__ best,
                                                 uint32_t kt0, uint32_t kt1) {
  __shared__ __align__(16) short As_hi[64 * 32];    // 4 KB
  __shared__ __align__(16) short As_lo[64 * 32];    // 4 KB
  __shared__ __align__(16) short Bs_hi[128 * 32];   // 8 KB
  __shared__ __align__(16) short Bs_lo[128 * 32];   // 8 KB

  // XCD-aware swizzle: XCD x owns c-blocks [16x, 16x+16) -> 2 MB B-set per L2
  const int flat = blockIdx.x;                 // 6656 = 8 * (16 * 52)
  const int xcd = flat & 7, slot = flat >> 3;  // slot in [0, 832)
  const int c_base = (xcd * 16 + (slot & 15)) * 128;
  const int j_base = (slot >> 4) * 64;

  const int t = threadIdx.x;
  const int lane = t & 63, w = t >> 6;

  // staging: wave w DMAs A rows [16w,16w+16) and B rows [32w,32w+32)
  const int ra = w * 16 + (lane >> 2);           // A row
  const int rb0 = w * 32 + (lane >> 2);          // B rows rb0, rb0+16
  const int rb1 = rb0 + 16;
  const int ua = (lane & 3) ^ ((ra >> 1) & 3);   // swizzle-inverted data unit
  const int ub0 = (lane & 3) ^ ((rb0 >> 1) & 3);
  const int ub1 = (lane & 3) ^ ((rb1 >> 1) & 3);
  const uint32_t offA = (uint32_t)(src_idx[min(j_base + ra, NH - 1)] * DK + ua * 8);
  const uint32_t offB0 = (uint32_t)((c_base + rb0) * DK + ub0 * 8);
  const uint32_t offB1 = (uint32_t)((c_base + rb1) * DK + ub1 * 8);
  short* dA  = &As_hi[w * 512];   // same offset valid for hi/lo pairs
  short* dAl = &As_lo[w * 512];
  short* dB  = &Bs_hi[w * 1024];
  short* dBl = &Bs_lo[w * 1024];

  // fragment roles: wave covers m-half mh (32 rows) x c-half ch (64 cols)
  const int mh = w >> 1, ch = w & 1;
  const int cl = lane & 15, q = lane >> 4;
  int foffA[2], foffB[4];
#pragma unroll
  for (int i = 0; i < 2; ++i) {
    int r = mh * 32 + cl + i * 16;
    foffA[i] = r * 32 + (q ^ ((r >> 1) & 3)) * 8;
  }
#pragma unroll
  for (int i = 0; i < 4; ++i) {
    int r = ch * 64 + cl + i * 16;
    foffB[i] = r * 32 + (q ^ ((r >> 1) & 3)) * 8;
  }

  // epilogue coordinates (needed for in-loop gumbel counters)
  const int q4 = q * 4;
  const int coff = c_base + ch * 64;
  const int roff = j_base + mh * 32;
  const uint32_t ccl = (uint32_t)(coff + cl);

  f32x4 acc[2][4];
#pragma unroll
  for (int mt = 0; mt < 2; ++mt)
#pragma unroll
    for (int nt = 0; nt < 4; ++nt) acc[mt][nt] = (f32x4){0.f, 0.f, 0.f, 0.f};

  float gum[32];   // gum[((mt*4+r)*4)+nt], filled 4 per K-chunk

  // prologue: DMA chunk 0
  glds16(zh + offA, dA);
  glds16(zl + offA, dAl);
  glds16(zh + offB0, dB);
  glds16(zh + offB1, dB + 512);
  glds16(zl + offB0, dBl);
  glds16(zl + offB1, dBl + 512);

#pragma unroll
  for (int kc = 0; kc < 8; ++kc) {
    __syncthreads();   // barrier1: chunk kc's DMA landed (issued a phase ago)

    short8 ah[2], al[2], bh[4], bl[4];
#pragma unroll
    for (int nt = 0; nt < 4; ++nt) {
      bh[nt] = *(const short8*)&Bs_hi[foffB[nt]];
      bl[nt] = *(const short8*)&Bs_lo[foffB[nt]];
    }
#pragma unroll
    for (int mt = 0; mt < 2; ++mt) {
      ah[mt] = *(const short8*)&As_hi[foffA[mt]];
      al[mt] = *(const short8*)&As_lo[foffA[mt]];
    }

    // ---- gumbels 0,1 of this chunk: their threefry VALU chains cover the
    // ds_read latency, so barrier2's lgkmcnt(0) drain is costless. Single
    // pin-wall for the pair -> the two chains interleave (2-way ILP).
    float gv0, gv1;
    {
      const int idx = kc * 4 + 0;
      const int mt = idx >> 4, r = (idx >> 2) & 3, nt = idx & 3;
      int gj = roff + mt * 16 + q4 + r;
      uint32_t p = (uint32_t)gj * (uint32_t)BN + ccl + (uint32_t)(nt * 16);
      gv0 = gumbel_at(kt0, kt1, p);
    }
    {
      const int idx = kc * 4 + 1;
      const int mt = idx >> 4, r = (idx >> 2) & 3, nt = idx & 3;
      int gj = roff + mt * 16 + q4 + r;
      uint32_t p = (uint32_t)gj * (uint32_t)BN + ccl + (uint32_t)(nt * 16);
      gv1 = gumbel_at(kt0, kt1, p);
    }
    asm volatile("" : "+v"(gv0), "+v"(gv1));
    gum[kc * 4 + 0] = gv0;
    gum[kc * 4 + 1] = gv1;

    __syncthreads();   // barrier2: all waves read LDS; safe to overwrite

    if (kc < 7) {      // issue chunk kc+1's DMA; lands during MFMA+gumbels
      const int ko = (kc + 1) * 32;
      glds16(zh + offA + ko, dA);
      glds16(zl + offA + ko, dAl);
      glds16(zh + offB0 + ko, dB);
      glds16(zh + offB1 + ko, dB + 512);
      glds16(zl + offB0 + ko, dBl);
      glds16(zl + offB1 + ko, dBl + 512);
    }

#pragma unroll
    for (int mt = 0; mt < 2; ++mt)
#pragma unroll
      for (int nt = 0; nt < 4; ++nt) {
        acc[mt][nt] = __builtin_amdgcn_mfma_f32_16x16x32_bf16(ah[mt], bh[nt], acc[mt][nt], 0, 0, 0);
        acc[mt][nt] = __builtin_amdgcn_mfma_f32_16x16x32_bf16(ah[mt], bl[nt], acc[mt][nt], 0, 0, 0);
        acc[mt][nt] = __builtin_amdgcn_mfma_f32_16x16x32_bf16(al[mt], bh[nt], acc[mt][nt], 0, 0, 0);
      }

    // ---- gumbels 2,3: co-issue with MFMA latency / DMA in flight ----
    float gv2, gv3;
    {
      const int idx = kc * 4 + 2;
      const int mt = idx >> 4, r = (idx >> 2) & 3, nt = idx & 3;
      int gj = roff + mt * 16 + q4 + r;
      uint32_t p = (uint32_t)gj * (uint32_t)BN + ccl + (uint32_t)(nt * 16);
      gv2 = gumbel_at(kt0, kt1, p);
    }
    {
      const int idx = kc * 4 + 3;
      const int mt = idx >> 4, r = (idx >> 2) & 3, nt = idx & 3;
      int gj = roff + mt * 16 + q4 + r;
      uint32_t p = (uint32_t)gj * (uint32_t)BN + ccl + (uint32_t)(nt * 16);
      gv3 = gumbel_at(kt0, kt1, p);
    }
    asm volatile("" : "+v"(gv2), "+v"(gv3));
    gum[kc * 4 + 2] = gv2;
    gum[kc * 4 + 3] = gv3;
  }

  // ---- lean epilogue: tot = fmaf(sim,10,gum); argmax over wave's 64 cols ----
#pragma unroll
  for (int mt = 0; mt < 2; ++mt)
#pragma unroll
    for (int r = 0; r < 4; ++r) {
      int gj = roff + mt * 16 + q4 + r;
      int s = src_idx[min(gj, NH - 1)];
      float bv = -INFINITY; uint32_t bc = 0;
#pragma unroll
      for (int nt = 0; nt < 4; ++nt) {
        uint32_t c = ccl + (uint32_t)(nt * 16);
        float tot = fmaf(acc[mt][nt][r], 10.0f, gum[((mt * 4 + r) * 4) + nt]);
        tot = ((int)c == s) ? -INFINITY : tot;         // diagonal mask
        if (tot > bv) { bv = tot; bc = c; }
      }
      unsigned long long key = packvc(bv, bc);
#pragma unroll
      for (int off = 1; off <= 8; off <<= 1) {        // reduce over 16 cl lanes
        unsigned long long o = __shfl_xor(key, off, 64);
        if (o > key) key = o;
      }
      if (cl == 0 && gj < NH) atomicMax(&best[gj], key);
    }
}

__global__ __launch_bounds__(64) void k_out(const float* __restrict__ z,
                                            const int* __restrict__ src_idx,
                                            const unsigned long long* __restrict__ best,
                                            float* __restrict__ out,
                                            uint32_t ka0, uint32_t ka1) {
  int j = blockIdx.x;
  int lane = threadIdx.x;
  int s = src_idx[j];
  int tgt = (int)(~((uint32_t)(best[j] & 0xFFFFFFFFull)));
  uint32_t bits = rand32_at(ka0, ka1, (uint32_t)j);
  float alpha = unif01_from_bits(bits) * 0.5f;   // uniform * MIX_ALPHA
  float om = 1.0f - alpha;
  float4 a = *(const float4*)&z[s * DK + lane * 4];
  float4 b = *(const float4*)&z[tgt * DK + lane * 4];
  float4 o;
  o.x = alpha * a.x + om * b.x;
  o.y = alpha * a.y + om * b.y;
  o.z = alpha * a.z + om * b.z;
  o.w = alpha * a.w + om * b.w;
  *(float4*)&out[j * DK + lane * 4] = o;
}

// ---------------------------------------------------------------------------
extern "C" void kernel_launch(void* const* d_in, const int* in_sizes, int n_in,
                              void* d_out, int out_size, void* d_ws, size_t ws_size,
                              hipStream_t stream) {
  const float* z = (const float*)d_in[0];
  float* out = (float*)d_out;
  char* ws = (char*)d_ws;
  // ws layout (~16.8 MB):
  int*                src_idx = (int*)(ws);                        // 16 KB
  unsigned long long* best    = (unsigned long long*)(ws + 16384); // 32 KB
  unsigned short*     zh      = (unsigned short*)(ws + 65536);     // 8.39 MB
  unsigned short*     zl      = (unsigned short*)(ws + 65536 + 8388608);

  // host-side threefry key derivation (partitionable scheme, verified round 1)
  uint32_t r0 = 0u, r1 = 42u;
  uint32_t ks0, ks1, kt0, kt1, ka0, ka1, k20, k21;
  tf2x32(r0, r1, 0u, 0u, ks0, ks1);   // k_src   = split(root,3)[0]
  tf2x32(r0, r1, 0u, 1u, kt0, kt1);   // k_tgt   = split(root,3)[1]
  tf2x32(r0, r1, 0u, 2u, ka0, ka1);   // k_alpha = split(root,3)[2]
  tf2x32(ks0, ks1, 0u, 1u, k20, k21); // split(k_src,2)[1] (randint lower bits)

  k_prep<<<dim3(BN / 4 + (NH + 255) / 256), dim3(256), 0, stream>>>(
      z, zh, zl, src_idx, best, k20, k21);
  k_main<<<dim3(NTILE), dim3(256), 0, stream>>>(zh, zl, src_idx, best, kt0, kt1);
  k_out <<<dim3(NH), dim3(64), 0, stream>>>(z, src_idx, best, out, ka0, ka1);
}